// Round 3
// baseline (40982.950 us; speedup 1.0000x reference)
//
#include <hip/hip_runtime.h>
#include <hip/hip_fp16.h>

#define BB 16
#define TT 1024
#define DD 1024
#define SS 512
#define KK 3072   // [x | ctx | h]

#define NBLK 256
#define NTHR 512

// d_out layout (floats): context [0,16384) | alignment [16384, 8404992) | termination [8404992,+16)
#define OUT_ALIGN 16384
#define OUT_TERM  8404992

typedef __attribute__((ext_vector_type(8))) short short8;     // 8 bf16 (4 VGPRs)
typedef __attribute__((ext_vector_type(4))) float floatx4;    // MFMA C/D
typedef __attribute__((ext_vector_type(2))) _Float16 half2v;  // v_dot2 operand

struct KParams {
  const float* x;      // (B,T,D) fp32
  const float* mem;    // (B,S,D) fp32
  const int*   lens;
  const float* W_ih;   // (4D, 2D)
  const float* W_hh;   // (4D, D)
  const float* b_ih;
  const float* b_hh;
  const float* Wg_w;   // (48, D)
  const float* Wg_b;
  float* out;
  unsigned* bar;        // flag barrier region (zeroed each call)
  unsigned short* xc0;  // (B, 3072) bf16 recurrent state [x|ctx|h]
  unsigned short* xc1;
  unsigned* wgbf;       // Wg_w packed as bf16 pairs (48*512 u32), built once in-kernel
};

__device__ __forceinline__ float sigf(float v) {
  return __builtin_amdgcn_rcpf(1.0f + __expf(-v));
}
__device__ __forceinline__ float tanhfast(float v) {  // exp/rcp tanh, no libm
  float a = fabsf(v);
  float e = __expf(-2.0f * a);
  float r = (1.0f - e) * __builtin_amdgcn_rcpf(1.0f + e);
  return v < 0.0f ? -r : r;
}

__device__ __forceinline__ unsigned short f2bf(float f) {  // RNE fp32->bf16
  unsigned u = __float_as_uint(f);
  return (unsigned short)((u + 0x7FFFu + ((u >> 16) & 1u)) >> 16);
}
__device__ __forceinline__ float bf2f(unsigned short h) {
  return __uint_as_float(((unsigned)h) << 16);
}
__device__ __forceinline__ unsigned pack2bf(float a, float b) {
  return (unsigned)f2bf(a) | ((unsigned)f2bf(b) << 16);
}

// PRODUCER side: agent-scope relaxed stores — write-through to the LLC coherence
// point (bypass L1/L2), so data is globally visible once vmcnt drains.
__device__ __forceinline__ void cstore_u32(unsigned* p2, unsigned v) {
  __hip_atomic_store(p2, v, __ATOMIC_RELAXED, __HIP_MEMORY_SCOPE_AGENT);
}
// Barrier flags only: uncached agent-scope load (must never hit a stale cache).
__device__ __forceinline__ unsigned cload_u32(const unsigned* p2) {
  return __hip_atomic_load(p2, __ATOMIC_RELAXED, __HIP_MEMORY_SCOPE_AGENT);
}

// CONSUMER side: after each grid barrier, one acquire-agent fence invalidates the
// (non-coherent, per-XCD) L1/L2 so PLAIN cacheable loads observe MALL-fresh data.
// This is the key change vs R1: the 96KB/step state broadcast is then served to
// 32 blocks per XCD from that XCD's L2 (one MSHR-coalesced MALL fill per line per
// XCD) instead of 256 separate MALL round trips per line.
__device__ __forceinline__ void acq_fence() {
  __builtin_amdgcn_fence(__ATOMIC_ACQUIRE, "agent");
}

// LDS-only barrier: s_barrier without the vmcnt(0) drain __syncthreads implies.
__device__ __forceinline__ void lds_barrier() {
  asm volatile("s_waitcnt lgkmcnt(0)\n\ts_barrier" ::: "memory");
}

// Decentralized 1-hop grid barrier: every block stores its epoch flag; threads
// 0..255 of every block poll all 256 flags directly. Leading __syncthreads drains
// vmcnt(0) per wave -> all prior agent stores are globally visible before the flag.
__device__ __forceinline__ void grid_barrier(unsigned* bar, unsigned ep, int blk) {
  __syncthreads();
  if (threadIdx.x == 0) cstore_u32(&bar[64 + blk * 32], ep);
  if (threadIdx.x < NBLK) {
    while (cload_u32(&bar[64 + threadIdx.x * 32]) < ep) __builtin_amdgcn_s_sleep(1);
  }
  __syncthreads();
}

union UF { unsigned long long u[2]; short8 s; };
struct AF8 { UF f[8]; };

// x-part (chunks 0..3) + h-part (chunks 4..7) fragment loads — PLAIN cacheable
// loads (L2-shared across the XCD after the acquire fence).
__device__ __forceinline__ void xh_load(const unsigned short* xc, int ab, AF8& A) {
  const unsigned long long* xb = (const unsigned long long*)xc + ab;
#pragma unroll
  for (int s2 = 0; s2 < 4; ++s2) {
    A.f[s2].u[0]     = xb[s2 * 8];
    A.f[s2].u[1]     = xb[s2 * 8 + 1];
    A.f[4 + s2].u[0] = xb[512 + s2 * 8];
    A.f[4 + s2].u[1] = xb[512 + s2 * 8 + 1];
  }
}
__device__ __forceinline__ void xh_mfma(const AF8& A, const short8* bfr,
                                        floatx4& A0, floatx4& A1) {
  floatx4 a0 = {0.f, 0.f, 0.f, 0.f}, a1 = {0.f, 0.f, 0.f, 0.f};
#pragma unroll
  for (int s2 = 0; s2 < 4; s2 += 2) {
    a0 = __builtin_amdgcn_mfma_f32_16x16x32_bf16(A.f[s2].s,     bfr[s2],     a0, 0, 0, 0);
    a1 = __builtin_amdgcn_mfma_f32_16x16x32_bf16(A.f[s2 + 1].s, bfr[s2 + 1], a1, 0, 0, 0);
    a0 = __builtin_amdgcn_mfma_f32_16x16x32_bf16(A.f[4 + s2].s,     bfr[8 + s2],     a0, 0, 0, 0);
    a1 = __builtin_amdgcn_mfma_f32_16x16x32_bf16(A.f[4 + s2 + 1].s, bfr[8 + s2 + 1], a1, 0, 0, 0);
  }
  A0 = a0; A1 = a1;
}

__global__ __launch_bounds__(NTHR, 2) void tts_kernel(KParams p) {
  extern __shared__ char smem[];
  half2v* memsh2 = (half2v*)smem;  // [256 s-pairs][64 d] fp16x2, 64 KiB

  __shared__ float redC[8 * 4 * 65 + 4];  // wave-partial C tiles
  __shared__ unsigned hshu[8 * 65];       // phase-C h (bf16 pairs), +1 pad word/row
  __shared__ float php[384];              // phi partials
  __shared__ float alsh[16], ksish[16], invbsh[16];
  __shared__ float Rsh[513];              // Rsh[s+1]=R(s); Rsh[0]=R(-1)
  __shared__ half2v wsh2[256];            // w(s) packed in s-pairs
  __shared__ float ctxp[8][64];
  __shared__ float bsh48[48];             // Wg_b

  const int t    = threadIdx.x;
  const int blk  = blockIdx.x;
  const int lane = t & 63;
  const int w    = t >> 6;     // wave id [0,8): K-slice w*128 in each region
  const int bbt  = blk & 15;   // batch this block serves in phase C
  const int dc   = blk >> 4;   // 64-wide d-chunk for ctx / x-copy

  // ---- one-time: B-fragments (weights) into registers as bf16 ----
  // chunk ki: region r3=ki>>2 (0=x,1=ctx,2=h), sub=ki&3; k0 = r3*1024 + w*128 + sub*32
  short8 bfr[12];
  {
    const int n = lane & 15;
    const int r = (n & 3) * 1024 + blk * 4 + (n >> 2);
    const int q = lane >> 4;
#pragma unroll
    for (int ki = 0; ki < 12; ++ki) {
      short8 v;
      const int k0 = (ki >> 2) * 1024 + w * 128 + (ki & 3) * 32 + q * 8;
#pragma unroll
      for (int j = 0; j < 8; ++j) {
        int k = k0 + j;
        float wv = (k < 2048) ? p.W_ih[(size_t)r * 2048 + k]
                              : p.W_hh[(size_t)r * 1024 + (k - 2048)];
        v[j] = (short)f2bf(wv);
      }
      bfr[ki] = v;
    }
  }
  // ---- one-time: biases ----
  float biasreg[4] = {0.f, 0.f, 0.f, 0.f};
  if (t < 64) {
    int dl = t & 3;
#pragma unroll
    for (int g = 0; g < 4; ++g) {
      int r = g * 1024 + blk * 4 + dl;
      biasreg[g] = p.b_ih[r] + p.b_hh[r];
    }
  }
  if (t < 48) bsh48[t] = p.Wg_b[t];
  // ---- one-time: memory[bbt, :, dc*64..+64) -> LDS as half2 s-pairs ----
  {
    int dl = t & 63, sp = t >> 6;
    for (int pr = sp; pr < 256; pr += 8) {
      const float* mp = p.mem + (size_t)bbt * SS * DD + (size_t)(2 * pr) * DD + dc * 64 + dl;
      half2v v;
      v.x = (_Float16)mp[0];
      v.y = (_Float16)mp[DD];
      memsh2[pr * 64 + dl] = v;
    }
  }
  // ---- one-time: xc0 = [x_0 | 0 | 0] ----
  if (t < 32) {
    int k = dc * 64 + 2 * t;
    const float* xs = p.x + (size_t)bbt * TT * DD + k;
    cstore_u32((unsigned*)(p.xc0 + bbt * KK + k), pack2bf(xs[0], xs[1]));
    cstore_u32((unsigned*)(p.xc0 + bbt * KK + 1024 + k), 0u);
    cstore_u32((unsigned*)(p.xc0 + bbt * KK + 2048 + k), 0u);
  }
  // ---- one-time: Wg_w fp32 -> bf16 pairs in workspace ----
  if (blk == 0) {
    for (int i = t; i < 48 * 512; i += NTHR)
      cstore_u32(&p.wgbf[i], pack2bf(p.Wg_w[2 * i], p.Wg_w[2 * i + 1]));
  }
  grid_barrier(p.bar, 1u, blk);
  acq_fence();  // invalidate stale L1/L2 (incl. lines cached by a previous replay)

  float c_val = 0.0f;  // LSTM cell state: thread t<64 owns (b=t>>2, d=blk*4+(t&3))
  unsigned ep = 1;
  unsigned short* xc_cur = p.xc0;
  unsigned short* xc_nxt = p.xc1;
  const int ab = ((lane & 15) * KK + w * 128 + (lane >> 4) * 8) >> 2;  // u64 frag base

  // Pre-loop: x_0 + h_{-1}(=0) gate contributions carried into step 0's phase A.
  floatx4 accXH0, accXH1;
  {
    AF8 a;
    xh_load(xc_cur, ab, a);
    xh_mfma(a, bfr, accXH0, accXH1);
  }

  for (int tstep = 0; tstep < TT; ++tstep) {
    // ================= Phase A: ctx-part MFMA + LSTM pointwise =================
    // Only the ctx third of K is on the post-barE path; x/h parts were carried in.
    {
      const unsigned long long* xb = (const unsigned long long*)xc_cur + ab;
      UF afc[4];
#pragma unroll
      for (int s2 = 0; s2 < 4; ++s2) {
        afc[s2].u[0] = xb[256 + s2 * 8];
        afc[s2].u[1] = xb[256 + s2 * 8 + 1];
      }
      floatx4 a0 = accXH0, a1 = accXH1;
      a0 = __builtin_amdgcn_mfma_f32_16x16x32_bf16(afc[0].s, bfr[4], a0, 0, 0, 0);
      a1 = __builtin_amdgcn_mfma_f32_16x16x32_bf16(afc[1].s, bfr[5], a1, 0, 0, 0);
      a0 = __builtin_amdgcn_mfma_f32_16x16x32_bf16(afc[2].s, bfr[6], a0, 0, 0, 0);
      a1 = __builtin_amdgcn_mfma_f32_16x16x32_bf16(afc[3].s, bfr[7], a1, 0, 0, 0);
      a0 += a1;
#pragma unroll
      for (int reg = 0; reg < 4; ++reg)
        redC[(w * 4 + reg) * 65 + lane] = a0[reg];
    }
    lds_barrier();
    if (t < 64) {  // pointwise LSTM for (b = t>>2, dl = t&3); h packed via shfl
      int b = t >> 2, dl = t & 3;
      float gate[4];
#pragma unroll
      for (int g = 0; g < 4; ++g) {
        int ls = (b >> 2) * 16 + (dl * 4 + g);
        float s = biasreg[g];
#pragma unroll
        for (int w2 = 0; w2 < 8; ++w2) s += redC[(w2 * 4 + (b & 3)) * 65 + ls];
        gate[g] = s;
      }
      c_val = sigf(gate[1]) * c_val + sigf(gate[0]) * tanhfast(gate[2]);
      float hv = sigf(gate[3]) * tanhfast(c_val);
      float hn = __shfl_down(hv, 1, 64);
      if ((t & 1) == 0)
        cstore_u32((unsigned*)(xc_nxt + b * KK + 2048 + blk * 4 + dl), pack2bf(hv, hn));
    } else if (t < 96) {
      if (tstep + 1 < TT) {  // prefetch x_{t+1} into xc_nxt (read at this step's phase C)
        int k = dc * 64 + 2 * (t - 64);
        const float* xs = p.x + (size_t)bbt * TT * DD + (size_t)(tstep + 1) * DD + k;
        cstore_u32((unsigned*)(xc_nxt + bbt * KK + k), pack2bf(xs[0], xs[1]));
      }
    }
    grid_barrier(p.bar, ++ep, blk);  // barH: h_t (and x_{t+1}) globally visible
    acq_fence();                     // L2 refreshed; plain loads below are coherent

    // ============ Phase C: phi -> window -> ctx; overlap next-step x/h MFMA ============
    // h staging load first (feeds the critical phi chain), then next-step x/h
    // fragment loads — all plain (XCD-L2-shared), consumed late.
    unsigned hword = ((const unsigned*)(xc_nxt + bbt * KK + 2048))[t];
    AF8 afx;
    xh_load(xc_nxt, ab, afx);
    __builtin_amdgcn_sched_barrier(0);
    hshu[(t >> 6) * 65 + (t & 63)] = hword;
    lds_barrier();
    if (t < 384) {  // phi partials: m = t>>3, part = t&7 (128 k each), bf16 weights
      int m = t >> 3, part = t & 7;
      const unsigned* wgp = p.wgbf + m * 512 + part * 64;
      const unsigned* hrow = hshu + part * 65;
      float s0 = 0.f, s1 = 0.f, s2 = 0.f, s3 = 0.f;
#pragma unroll 4
      for (int i = 0; i < 64; i += 4) {
        unsigned u0 = hrow[i],     g0 = wgp[i];
        unsigned u1 = hrow[i + 1], g1 = wgp[i + 1];
        unsigned u2 = hrow[i + 2], g2 = wgp[i + 2];
        unsigned u3 = hrow[i + 3], g3 = wgp[i + 3];
        s0 += bf2f((unsigned short)u0) * bf2f((unsigned short)g0)
            + bf2f((unsigned short)(u0 >> 16)) * bf2f((unsigned short)(g0 >> 16));
        s1 += bf2f((unsigned short)u1) * bf2f((unsigned short)g1)
            + bf2f((unsigned short)(u1 >> 16)) * bf2f((unsigned short)(g1 >> 16));
        s2 += bf2f((unsigned short)u2) * bf2f((unsigned short)g2)
            + bf2f((unsigned short)(u2 >> 16)) * bf2f((unsigned short)(g2 >> 16));
        s3 += bf2f((unsigned short)u3) * bf2f((unsigned short)g3)
            + bf2f((unsigned short)(u3 >> 16)) * bf2f((unsigned short)(g3 >> 16));
      }
      php[t] = (s0 + s1) + (s2 + s3);
    }
    lds_barrier();
    if (t < 64) {  // merged: phi reduce + softmax + exps + R(-1), all in wave 0
      float s = 0.f;
      if (t < 48) {
        s = bsh48[t];
#pragma unroll
        for (int i = 0; i < 8; ++i) s += php[t * 8 + i];
      }
      float mx = s;
#pragma unroll
      for (int o = 1; o < 16; o <<= 1) mx = fmaxf(mx, __shfl_xor(mx, o, 64));
      float e = __expf(s - mx);
      float sm = e;
#pragma unroll
      for (int o = 1; o < 16; o <<= 1) sm += __shfl_xor(sm, o, 64);
      float alpha_v = e * __builtin_amdgcn_rcpf(sm);
      float ksi_v   = __expf(s);
      float invb_v  = __expf(-s);
      if (t >= 32) { if (t < 48) alsh[t - 32] = alpha_v; }
      else if (t < 16) ksish[t] = ksi_v;
      else invbsh[t - 16] = invb_v;
      int m = t & 15;
      float am = __shfl(alpha_v, 32 + m, 64);
      float km = __shfl(ksi_v, m, 64);
      float bm = __shfl(invb_v, 16 + m, 64);
      float term = am * sigf((-0.5f - km) * bm);
#pragma unroll
      for (int o = 1; o < 16; o <<= 1) term += __shfl_xor(term, o, 64);
      if (t == 48) Rsh[0] = term;
    }
    lds_barrier();
    {  // R(s) + w(s)=R(s)-R(s-1) via in-wave shuffles; pack wsh2; alignment store
      float su = (float)t;
      float rv0 = 0.f, rv1 = 0.f;
#pragma unroll
      for (int m = 0; m < 16; m += 2) {
        rv0 += alsh[m]     * sigf((su + 0.5f - ksish[m])     * invbsh[m]);
        rv1 += alsh[m + 1] * sigf((su + 0.5f - ksish[m + 1]) * invbsh[m + 1]);
      }
      float rv = rv0 + rv1;
      float rvp = __shfl_up(rv, 1, 64);   // invalid at lane 0 — fixed next stage
      float rvn = __shfl_down(rv, 1, 64);
      Rsh[t + 1] = rv;
      if ((t & 1) == 0) {
        half2v v2;
        v2.x = (_Float16)(rv - rvp);
        v2.y = (_Float16)(rvn - rv);
        wsh2[t >> 1] = v2;
      }
      if (dc == 0 && (t & 63) != 0)
        p.out[OUT_ALIGN + ((size_t)bbt * TT + tstep) * SS + t] = rv - rvp;
    }
    lds_barrier();
    {  // ctx partials; wave-boundary w pairs recomputed from Rsh (lane-0 shfl gap)
      if (dc == 0 && t < 8)
        p.out[OUT_ALIGN + ((size_t)bbt * TT + tstep) * SS + 64 * t] =
            Rsh[64 * t + 1] - Rsh[64 * t];
      if (tstep == TT - 1 && dc == 0 && t == 0)
        p.out[OUT_TERM + bbt] = 1.0f - Rsh[p.lens[bbt]];
      int dl = t & 63, sp = t >> 6;
      float b0 = Rsh[64 * sp], b1 = Rsh[64 * sp + 1], b2 = Rsh[64 * sp + 2];
      half2v w0;
      w0.x = (_Float16)(b1 - b0);
      w0.y = (_Float16)(b2 - b1);
      float s0 = __builtin_amdgcn_fdot2(memsh2[(sp * 32) * 64 + dl], w0, 0.f, false);
      float s1 = 0.f;
#pragma unroll
      for (int q = 1; q < 32; ++q) {
        int pr = sp * 32 + q;
        float v = __builtin_amdgcn_fdot2(memsh2[pr * 64 + dl], wsh2[pr],
                                         (q & 1) ? s1 : s0, false);
        if (q & 1) s1 = v; else s0 = v;
      }
      ctxp[sp][dl] = s0 + s1;
    }
    lds_barrier();
    if (t < 64) {  // ctx reduce + coherent store (+ context output at last step)
      float cv = 0.f;
#pragma unroll
      for (int pp = 0; pp < 8; ++pp) cv += ctxp[pp][t];
      if (tstep == TT - 1) p.out[bbt * DD + dc * 64 + t] = cv;
      float cvn = __shfl_down(cv, 1, 64);
      if ((t & 1) == 0)
        cstore_u32((unsigned*)(xc_nxt + bbt * KK + 1024 + dc * 64 + t), pack2bf(cv, cvn));
    }
    // next-step x/h gate MFMAs (register-only; fragments loaded at phase C top).
    __builtin_amdgcn_sched_barrier(0);
    xh_mfma(afx, bfr, accXH0, accXH1);
    grid_barrier(p.bar, ++ep, blk);  // barE: ctx_t globally visible
    acq_fence();

    unsigned short* tmp = xc_cur; xc_cur = xc_nxt; xc_nxt = tmp;
  }
}

extern "C" void kernel_launch(void* const* d_in, const int* in_sizes, int n_in,
                              void* d_out, int out_size, void* d_ws, size_t ws_size,
                              hipStream_t stream) {
  (void)in_sizes; (void)n_in; (void)out_size; (void)ws_size;
  KParams p;
  p.x    = (const float*)d_in[0];
  p.mem  = (const float*)d_in[1];
  p.lens = (const int*)d_in[2];
  p.W_ih = (const float*)d_in[3];
  p.W_hh = (const float*)d_in[4];
  p.b_ih = (const float*)d_in[5];
  p.b_hh = (const float*)d_in[6];
  p.Wg_w = (const float*)d_in[7];
  p.Wg_b = (const float*)d_in[8];
  p.out  = (float*)d_out;
  p.bar  = (unsigned*)d_ws;
  p.xc0  = (unsigned short*)((char*)d_ws + 36864);
  p.xc1  = (unsigned short*)((char*)d_ws + 36864 + BB * KK * 2);
  p.wgbf = (unsigned*)((char*)d_ws + 36864 + 2 * BB * KK * 2);

  hipMemsetAsync(d_ws, 0, 36864, stream);  // zero barrier flags every call

  const unsigned dynLds = 65536;  // half2 memory slice
  hipFuncSetAttribute((const void*)tts_kernel, hipFuncAttributeMaxDynamicSharedMemorySize,
                      (int)dynLds);

  void* args[] = { &p };
  hipLaunchCooperativeKernel((const void*)tts_kernel, dim3(NBLK), dim3(NTHR), args, dynLds,
                             stream);
}

// Round 4
// 16189.317 us; speedup vs baseline: 2.5315x; 2.5315x over previous
//
#include <hip/hip_runtime.h>
#include <hip/hip_fp16.h>

#define BB 16
#define TT 1024
#define DD 1024
#define SS 512
#define KK2 2048  // per-batch exchange state: [ctx | h] bf16

#define NBLK 128
#define NTHR 512

// d_out layout (floats): context [0,16384) | alignment [16384, 8404992) | termination [8404992,+16)
#define OUT_ALIGN 16384
#define OUT_TERM  8404992

typedef __attribute__((ext_vector_type(8))) short short8;     // 8 bf16 (4 VGPRs)
typedef __attribute__((ext_vector_type(4))) float floatx4;    // MFMA C/D + vec loads
typedef __attribute__((ext_vector_type(2))) _Float16 half2v;  // v_dot2 operand

struct KParams {
  const float* x;      // (B,T,D) fp32
  const float* mem;    // (B,S,D) fp32
  const int*   lens;
  const float* W_ih;   // (4D, 2D)
  const float* W_hh;   // (4D, D)
  const float* b_ih;
  const float* b_hh;
  const float* Wg_w;   // (48, D)
  const float* Wg_b;
  float* out;
  unsigned* bar;        // flag barrier region (zeroed each call)
  unsigned short* xc0;  // (B, 2048) bf16 recurrent state [ctx|h]
  unsigned short* xc1;
  unsigned* wgbf;       // Wg_w packed as bf16 pairs (48*512 u32), built once in-kernel
};

__device__ __forceinline__ float sigf(float v) {
  return __builtin_amdgcn_rcpf(1.0f + __expf(-v));
}
__device__ __forceinline__ float tanhfast(float v) {  // exp/rcp tanh, no libm
  float a = fabsf(v);
  float e = __expf(-2.0f * a);
  float r = (1.0f - e) * __builtin_amdgcn_rcpf(1.0f + e);
  return v < 0.0f ? -r : r;
}

__device__ __forceinline__ unsigned short f2bf(float f) {  // RNE fp32->bf16
  unsigned u = __float_as_uint(f);
  return (unsigned short)((u + 0x7FFFu + ((u >> 16) & 1u)) >> 16);
}
__device__ __forceinline__ float bf2f(unsigned short h) {
  return __uint_as_float(((unsigned)h) << 16);
}
__device__ __forceinline__ unsigned pack2bf(float a, float b) {
  return (unsigned)f2bf(a) | ((unsigned)f2bf(b) << 16);
}
// HW packed RNE fp32->2xbf16 (same rounding as f2bf, 1 instr)
__device__ __forceinline__ unsigned cvtpk(float a, float b) {
  unsigned r;
  asm volatile("v_cvt_pk_bf16_f32 %0, %1, %2" : "=v"(r) : "v"(a), "v"(b));
  return r;
}

// Agent-scope relaxed atomics: uncached loads/stores at the LLC coherence point.
__device__ __forceinline__ void cstore_u32(unsigned* p2, unsigned v) {
  __hip_atomic_store(p2, v, __ATOMIC_RELAXED, __HIP_MEMORY_SCOPE_AGENT);
}
__device__ __forceinline__ unsigned cload_u32(const unsigned* p2) {
  return __hip_atomic_load(p2, __ATOMIC_RELAXED, __HIP_MEMORY_SCOPE_AGENT);
}
__device__ __forceinline__ unsigned long long cload_u64(const unsigned long long* p2) {
  return __hip_atomic_load(p2, __ATOMIC_RELAXED, __HIP_MEMORY_SCOPE_AGENT);
}

// LDS-only barrier: s_barrier without the vmcnt(0) drain __syncthreads implies —
// outstanding global loads ride across phase-C stage barriers.
__device__ __forceinline__ void lds_barrier() {
  asm volatile("s_waitcnt lgkmcnt(0)\n\ts_barrier" ::: "memory");
}

// Decentralized 1-hop grid barrier (128 flags, 64 pollers/block to limit MALL
// poll pressure). Leading __syncthreads drains vmcnt per wave -> prior agent
// stores globally visible before the flag store. Monotonic epochs.
__device__ __forceinline__ void grid_barrier(unsigned* bar, unsigned ep, int blk) {
  __syncthreads();
  if (threadIdx.x == 0) cstore_u32(&bar[64 + blk * 32], ep);
  if (threadIdx.x < 64) {
    while (cload_u32(&bar[64 + (int)threadIdx.x * 32]) < ep) __builtin_amdgcn_s_sleep(1);
    while (cload_u32(&bar[64 + ((int)threadIdx.x + 64) * 32]) < ep) __builtin_amdgcn_s_sleep(1);
  }
  __syncthreads();
}

union UF { unsigned w[4]; unsigned long long u[2]; short8 s; };

#define MFMA16 __builtin_amdgcn_mfma_f32_16x16x32_bf16

// 16 MFMAs: x-region (chunks 0-3) + h-region (chunks 8-11), both column-tiles.
__device__ __forceinline__ void xh_mfma(const UF* xf, const UF* hf, const short8* bfr,
                                        floatx4& a00, floatx4& a01,
                                        floatx4& a10, floatx4& a11) {
  floatx4 z = {0.f, 0.f, 0.f, 0.f};
  a00 = z; a01 = z; a10 = z; a11 = z;
  a00 = MFMA16(xf[0].s, bfr[0],  a00, 0, 0, 0); a01 = MFMA16(xf[1].s, bfr[1],  a01, 0, 0, 0);
  a10 = MFMA16(xf[0].s, bfr[12], a10, 0, 0, 0); a11 = MFMA16(xf[1].s, bfr[13], a11, 0, 0, 0);
  a00 = MFMA16(xf[2].s, bfr[2],  a00, 0, 0, 0); a01 = MFMA16(xf[3].s, bfr[3],  a01, 0, 0, 0);
  a10 = MFMA16(xf[2].s, bfr[14], a10, 0, 0, 0); a11 = MFMA16(xf[3].s, bfr[15], a11, 0, 0, 0);
  a00 = MFMA16(hf[0].s, bfr[8],  a00, 0, 0, 0); a01 = MFMA16(hf[1].s, bfr[9],  a01, 0, 0, 0);
  a10 = MFMA16(hf[0].s, bfr[20], a10, 0, 0, 0); a11 = MFMA16(hf[1].s, bfr[21], a11, 0, 0, 0);
  a00 = MFMA16(hf[2].s, bfr[10], a00, 0, 0, 0); a01 = MFMA16(hf[3].s, bfr[11], a01, 0, 0, 0);
  a10 = MFMA16(hf[2].s, bfr[22], a10, 0, 0, 0); a11 = MFMA16(hf[3].s, bfr[23], a11, 0, 0, 0);
}

__global__ __launch_bounds__(NTHR, 2) void tts_kernel(KParams p) {
  extern __shared__ char smem[];
  half2v* memsh2 = (half2v*)smem;  // [256 s-pairs][128 d] fp16x2, 128 KiB

  __shared__ float redC[64 * 65 + 4];     // wave-partial C tiles (8w x 2tiles x 4reg)
  __shared__ unsigned hshu[8 * 65];       // phase-C h (bf16 pairs), +1 pad word/row
  __shared__ float php[384];              // phi partials
  __shared__ float alsh[16], ksish[16], invbsh[16];
  __shared__ float Rsh[513];              // Rsh[s+1]=R(s); Rsh[0]=R(-1)
  __shared__ half2v wsh2[256];            // w(s) packed in s-pairs
  __shared__ float ctxp[4][128];
  __shared__ float bsh48[48];             // Wg_b

  const int t    = threadIdx.x;
  const int blk  = blockIdx.x;
  const int lane = t & 63;
  const int w    = t >> 6;     // wave id [0,8): K-slice w*128 in each region
  const int bbt  = blk & 15;   // batch this block serves in phase C
  const int dc   = blk >> 4;   // [0,8): 128-wide d-chunk for ctx

  // ---- one-time: B-fragments (weights), 2 column-tiles x 12 chunks ----
  // tile nt covers W-rows r = (n&3)*1024 + blk*8 + nt*4 + (n>>2), n = lane&15.
  // chunk ki: region ki>>2 (0=x,1=ctx,2=h), k0 = (ki>>2)*1024 + w*128 + (ki&3)*32
  short8 bfr[24];
  {
    const int n = lane & 15;
    const int q = lane >> 4;
#pragma unroll
    for (int nt = 0; nt < 2; ++nt) {
      const int r = (n & 3) * 1024 + blk * 8 + nt * 4 + (n >> 2);
#pragma unroll
      for (int ki = 0; ki < 12; ++ki) {
        short8 v;
        const int k0 = (ki >> 2) * 1024 + w * 128 + (ki & 3) * 32 + q * 8;
#pragma unroll
        for (int j = 0; j < 8; ++j) {
          int k = k0 + j;
          float wv = (k < 2048) ? p.W_ih[(size_t)r * 2048 + k]
                                : p.W_hh[(size_t)r * 1024 + (k - 2048)];
          v[j] = (short)f2bf(wv);
        }
        bfr[nt * 12 + ki] = v;
      }
    }
  }
  // ---- one-time: biases for (b = t>>3, dl = t&7) ----
  float biasreg[4] = {0.f, 0.f, 0.f, 0.f};
  if (t < 128) {
    int dl = t & 7;
#pragma unroll
    for (int g = 0; g < 4; ++g) {
      int r = g * 1024 + blk * 8 + dl;
      biasreg[g] = p.b_ih[r] + p.b_hh[r];
    }
  }
  if (t < 48) bsh48[t] = p.Wg_b[t];
  // ---- one-time: memory[bbt, :, dc*128..+128) -> LDS as half2 s-pairs ----
  {
    int dl = t & 127, sp = t >> 7;
    for (int pr = sp; pr < 256; pr += 4) {
      const float* mp = p.mem + (size_t)bbt * SS * DD + (size_t)(2 * pr) * DD + dc * 128 + dl;
      half2v v;
      v.x = (_Float16)mp[0];
      v.y = (_Float16)mp[DD];
      memsh2[pr * 128 + dl] = v;
    }
  }
  // ---- one-time: Wg_w fp32 -> bf16 pairs in workspace ----
  if (blk == 0) {
    for (int i = t; i < 48 * 512; i += NTHR)
      cstore_u32(&p.wgbf[i], pack2bf(p.Wg_w[2 * i], p.Wg_w[2 * i + 1]));
  }
  grid_barrier(p.bar, 1u, blk);  // xc0 (memset zeros) + wgbf visible

  float c_val = 0.0f;  // LSTM cell state: thread t<128 owns (b=t>>3, d=blk*8+(t&7))
  unsigned ep = 1;
  unsigned short* xc_cur = p.xc0;
  unsigned short* xc_nxt = p.xc1;
  // per-lane fragment bases: A-row = batch = lane&15, k = w*128 + (lane>>4)*8
  const int ab2 = ((lane & 15) * KK2 + w * 128 + ((lane >> 4) * 8)) >> 2;  // u64 units
  const float* xrow = p.x + (size_t)(lane & 15) * TT * DD + w * 128 + ((lane >> 4) * 8);

  // Pre-loop: x_0 (direct, cacheable) + h_{-1}(=0) gate contributions.
  floatx4 acc00, acc01, acc10, acc11;
  {
    UF xf[4], hf[4];
#pragma unroll
    for (int sub = 0; sub < 4; ++sub) {
      floatx4 lo = *(const floatx4*)(xrow + sub * 32);
      floatx4 hi = *(const floatx4*)(xrow + sub * 32 + 4);
      xf[sub].w[0] = cvtpk(lo[0], lo[1]); xf[sub].w[1] = cvtpk(lo[2], lo[3]);
      xf[sub].w[2] = cvtpk(hi[0], hi[1]); xf[sub].w[3] = cvtpk(hi[2], hi[3]);
    }
    const unsigned long long* hb = (const unsigned long long*)p.xc0 + ab2 + 256;
#pragma unroll
    for (int sub = 0; sub < 4; ++sub) {
      hf[sub].u[0] = cload_u64(hb + sub * 8);
      hf[sub].u[1] = cload_u64(hb + sub * 8 + 1);
    }
    xh_mfma(xf, hf, bfr, acc00, acc01, acc10, acc11);
  }

  for (int tstep = 0; tstep < TT; ++tstep) {
    // ================= Phase A: ctx-part MFMA + LSTM pointwise =================
    {
      const unsigned long long* cb = (const unsigned long long*)xc_cur + ab2;
      UF fc[4];
#pragma unroll
      for (int sub = 0; sub < 4; ++sub) {
        fc[sub].u[0] = cload_u64(cb + sub * 8);
        fc[sub].u[1] = cload_u64(cb + sub * 8 + 1);
      }
      floatx4 c00 = acc00, c01 = acc01, c10 = acc10, c11 = acc11;
      c00 = MFMA16(fc[0].s, bfr[4],  c00, 0, 0, 0); c01 = MFMA16(fc[1].s, bfr[5],  c01, 0, 0, 0);
      c10 = MFMA16(fc[0].s, bfr[16], c10, 0, 0, 0); c11 = MFMA16(fc[1].s, bfr[17], c11, 0, 0, 0);
      c00 = MFMA16(fc[2].s, bfr[6],  c00, 0, 0, 0); c01 = MFMA16(fc[3].s, bfr[7],  c01, 0, 0, 0);
      c10 = MFMA16(fc[2].s, bfr[18], c10, 0, 0, 0); c11 = MFMA16(fc[3].s, bfr[19], c11, 0, 0, 0);
      c00 += c01; c10 += c11;
#pragma unroll
      for (int reg = 0; reg < 4; ++reg) {
        redC[(w * 8 + reg) * 65 + lane]     = c00[reg];
        redC[(w * 8 + 4 + reg) * 65 + lane] = c10[reg];
      }
    }
    lds_barrier();
    if (t < 128) {  // pointwise LSTM for (b = t>>3, dl = t&7)
      int b = t >> 3, dl = t & 7, nt = dl >> 2, dl4 = dl & 3;
      int row = nt * 4 + (b & 3);
      float gate[4];
#pragma unroll
      for (int g = 0; g < 4; ++g) {
        int ls = ((b >> 2) << 4) | (dl4 * 4 + g);
        float s = biasreg[g];
#pragma unroll
        for (int w2 = 0; w2 < 8; ++w2) s += redC[(w2 * 8 + row) * 65 + ls];
        gate[g] = s;
      }
      c_val = sigf(gate[1]) * c_val + sigf(gate[0]) * tanhfast(gate[2]);
      float hv = sigf(gate[3]) * tanhfast(c_val);
      float hn = __shfl_down(hv, 1, 64);
      if ((t & 1) == 0)
        cstore_u32((unsigned*)(xc_nxt + b * KK2 + 1024 + blk * 8 + dl), pack2bf(hv, hn));
    }
    grid_barrier(p.bar, ++ep, blk);  // barH: h_t globally visible

    // ============ Phase C: phi -> window -> ctx; next-step frags in flight ============
    // 1) critical h words for phi (agent), 2) h frags for t+1 (agent),
    // 3) x frags for t+1 (plain fp32, L2-cacheable) — converted at the end.
    unsigned long long hword = 0;
    if (t < 256) hword = cload_u64((const unsigned long long*)xc_nxt + bbt * 512 + 256 + t);
    UF hf[4];
    floatx4 xlo[4], xhi[4];
    if (tstep + 1 < TT) {
      const unsigned long long* hb = (const unsigned long long*)xc_nxt + ab2 + 256;
#pragma unroll
      for (int sub = 0; sub < 4; ++sub) {
        hf[sub].u[0] = cload_u64(hb + sub * 8);
        hf[sub].u[1] = cload_u64(hb + sub * 8 + 1);
      }
      const float* xp = xrow + (size_t)(tstep + 1) * DD;
#pragma unroll
      for (int sub = 0; sub < 4; ++sub) {
        xlo[sub] = *(const floatx4*)(xp + sub * 32);
        xhi[sub] = *(const floatx4*)(xp + sub * 32 + 4);
      }
    }
    if (t < 256) {
      int row = t >> 5, col = (t & 31) * 2;
      hshu[row * 65 + col]     = (unsigned)hword;
      hshu[row * 65 + col + 1] = (unsigned)(hword >> 32);
    }
    lds_barrier();
    if (t < 384) {  // phi partials: m = t>>3, part = t&7 (128 k each), bf16 weights
      int m = t >> 3, part = t & 7;
      const unsigned* wgp = p.wgbf + m * 512 + part * 64;
      const unsigned* hrow = hshu + part * 65;
      float s0 = 0.f, s1 = 0.f, s2 = 0.f, s3 = 0.f;
#pragma unroll 4
      for (int i = 0; i < 64; i += 4) {
        unsigned u0 = hrow[i],     g0 = wgp[i];
        unsigned u1 = hrow[i + 1], g1 = wgp[i + 1];
        unsigned u2 = hrow[i + 2], g2 = wgp[i + 2];
        unsigned u3 = hrow[i + 3], g3 = wgp[i + 3];
        s0 += bf2f((unsigned short)u0) * bf2f((unsigned short)g0)
            + bf2f((unsigned short)(u0 >> 16)) * bf2f((unsigned short)(g0 >> 16));
        s1 += bf2f((unsigned short)u1) * bf2f((unsigned short)g1)
            + bf2f((unsigned short)(u1 >> 16)) * bf2f((unsigned short)(g1 >> 16));
        s2 += bf2f((unsigned short)u2) * bf2f((unsigned short)g2)
            + bf2f((unsigned short)(u2 >> 16)) * bf2f((unsigned short)(g2 >> 16));
        s3 += bf2f((unsigned short)u3) * bf2f((unsigned short)g3)
            + bf2f((unsigned short)(u3 >> 16)) * bf2f((unsigned short)(g3 >> 16));
      }
      php[t] = (s0 + s1) + (s2 + s3);
    }
    lds_barrier();
    if (t < 64) {  // merged: phi reduce + softmax + exps + R(-1), all in wave 0
      float s = 0.f;
      if (t < 48) {
        s = bsh48[t];
#pragma unroll
        for (int i = 0; i < 8; ++i) s += php[t * 8 + i];
      }
      float mx = s;
#pragma unroll
      for (int o = 1; o < 16; o <<= 1) mx = fmaxf(mx, __shfl_xor(mx, o, 64));
      float e = __expf(s - mx);
      float sm = e;
#pragma unroll
      for (int o = 1; o < 16; o <<= 1) sm += __shfl_xor(sm, o, 64);
      float alpha_v = e * __builtin_amdgcn_rcpf(sm);
      float ksi_v   = __expf(s);
      float invb_v  = __expf(-s);
      if (t >= 32) { if (t < 48) alsh[t - 32] = alpha_v; }
      else if (t < 16) ksish[t] = ksi_v;
      else invbsh[t - 16] = invb_v;
      int m = t & 15;
      float am = __shfl(alpha_v, 32 + m, 64);
      float km = __shfl(ksi_v, m, 64);
      float bm = __shfl(invb_v, 16 + m, 64);
      float term = am * sigf((-0.5f - km) * bm);
#pragma unroll
      for (int o = 1; o < 16; o <<= 1) term += __shfl_xor(term, o, 64);
      if (t == 48) Rsh[0] = term;
    }
    lds_barrier();
    {  // R(s) + w(s)=R(s)-R(s-1) via in-wave shuffles; pack wsh2; alignment store
      float su = (float)t;
      float rv0 = 0.f, rv1 = 0.f;
#pragma unroll
      for (int m = 0; m < 16; m += 2) {
        rv0 += alsh[m]     * sigf((su + 0.5f - ksish[m])     * invbsh[m]);
        rv1 += alsh[m + 1] * sigf((su + 0.5f - ksish[m + 1]) * invbsh[m + 1]);
      }
      float rv = rv0 + rv1;
      float rvp = __shfl_up(rv, 1, 64);   // invalid at lane 0 — fixed below via Rsh
      float rvn = __shfl_down(rv, 1, 64);
      Rsh[t + 1] = rv;
      if ((t & 1) == 0) {
        half2v v2;
        v2.x = (_Float16)(rv - rvp);
        v2.y = (_Float16)(rvn - rv);
        wsh2[t >> 1] = v2;
      }
      if (dc == 0 && (t & 63) != 0)
        p.out[OUT_ALIGN + ((size_t)bbt * TT + tstep) * SS + t] = rv - rvp;
    }
    lds_barrier();
    {  // ctx partials; wave-boundary w entries (pr%32==0) recomputed from Rsh
      if (dc == 0 && t < 8)
        p.out[OUT_ALIGN + ((size_t)bbt * TT + tstep) * SS + 64 * t] =
            Rsh[64 * t + 1] - Rsh[64 * t];
      if (tstep == TT - 1 && dc == 0 && t == 0)
        p.out[OUT_TERM + bbt] = 1.0f - Rsh[p.lens[bbt]];
      int dl = t & 127, sp = t >> 7;
      const int pb = sp * 64;
      half2v wa = wsh2[pb];       wa.x = (_Float16)(Rsh[2 * pb + 1] - Rsh[2 * pb]);
      half2v wb = wsh2[pb + 32];  wb.x = (_Float16)(Rsh[2 * pb + 65] - Rsh[2 * pb + 64]);
      float s0 = __builtin_amdgcn_fdot2(memsh2[pb * 128 + dl], wa, 0.f, false);
      float s1 = __builtin_amdgcn_fdot2(memsh2[(pb + 32) * 128 + dl], wb, 0.f, false);
#pragma unroll 8
      for (int q = 1; q < 32; ++q) {
        s0 = __builtin_amdgcn_fdot2(memsh2[(pb + q) * 128 + dl],      wsh2[pb + q],      s0, false);
        s1 = __builtin_amdgcn_fdot2(memsh2[(pb + 32 + q) * 128 + dl], wsh2[pb + 32 + q], s1, false);
      }
      ctxp[sp][dl] = s0 + s1;
    }
    lds_barrier();
    if (t < 128) {  // ctx reduce + agent store (+ context output at last step)
      float cv = ctxp[0][t] + ctxp[1][t] + ctxp[2][t] + ctxp[3][t];
      if (tstep == TT - 1) p.out[bbt * DD + dc * 128 + t] = cv;
      float cvn = __shfl_down(cv, 1, 64);
      if ((t & 1) == 0)
        cstore_u32((unsigned*)(xc_nxt + bbt * KK2 + dc * 128 + t), pack2bf(cv, cvn));
    }
    // next-step x/h gate MFMAs (register-only; loads issued at phase-C top).
    __builtin_amdgcn_sched_barrier(0);
    if (tstep + 1 < TT) {
      UF xf[4];
#pragma unroll
      for (int sub = 0; sub < 4; ++sub) {
        xf[sub].w[0] = cvtpk(xlo[sub][0], xlo[sub][1]);
        xf[sub].w[1] = cvtpk(xlo[sub][2], xlo[sub][3]);
        xf[sub].w[2] = cvtpk(xhi[sub][0], xhi[sub][1]);
        xf[sub].w[3] = cvtpk(xhi[sub][2], xhi[sub][3]);
      }
      xh_mfma(xf, hf, bfr, acc00, acc01, acc10, acc11);
    }
    grid_barrier(p.bar, ++ep, blk);  // barE: ctx_t globally visible

    unsigned short* tmp = xc_cur; xc_cur = xc_nxt; xc_nxt = tmp;
  }
}

extern "C" void kernel_launch(void* const* d_in, const int* in_sizes, int n_in,
                              void* d_out, int out_size, void* d_ws, size_t ws_size,
                              hipStream_t stream) {
  (void)in_sizes; (void)n_in; (void)out_size; (void)ws_size;
  KParams p;
  p.x    = (const float*)d_in[0];
  p.mem  = (const float*)d_in[1];
  p.lens = (const int*)d_in[2];
  p.W_ih = (const float*)d_in[3];
  p.W_hh = (const float*)d_in[4];
  p.b_ih = (const float*)d_in[5];
  p.b_hh = (const float*)d_in[6];
  p.Wg_w = (const float*)d_in[7];
  p.Wg_b = (const float*)d_in[8];
  p.out  = (float*)d_out;
  p.bar  = (unsigned*)d_ws;
  p.xc0  = (unsigned short*)((char*)d_ws + 36864);                  // 16*2048*2 = 64 KiB
  p.xc1  = (unsigned short*)((char*)d_ws + 36864 + 65536);
  p.wgbf = (unsigned*)((char*)d_ws + 36864 + 131072);

  // zero barrier flags + xc0 (ctx_{-1} = h_{-1} = 0)
  hipMemsetAsync(d_ws, 0, 36864 + 65536, stream);

  const unsigned dynLds = 131072;  // half2 memory slice [256][128]
  hipFuncSetAttribute((const void*)tts_kernel, hipFuncAttributeMaxDynamicSharedMemorySize,
                      (int)dynLds);

  void* args[] = { &p };
  hipLaunchCooperativeKernel((const void*)tts_kernel, dim3(NBLK), dim3(NTHR), args, dynLds,
                             stream);
}

// Round 6
// 13334.384 us; speedup vs baseline: 3.0735x; 1.2141x over previous
//
#include <hip/hip_runtime.h>
#include <hip/hip_fp16.h>

#define BB 16
#define TT 1024
#define DD 1024
#define SS 512
#define KK2 2048  // per-batch exchange state: [ctx | h] bf16

#define NBLK 128
#define NTHR 512

// d_out layout (floats): context [0,16384) | alignment [16384, 8404992) | termination [8404992,+16)
#define OUT_ALIGN 16384
#define OUT_TERM  8404992

typedef __attribute__((ext_vector_type(8))) short short8;     // 8 bf16 (4 VGPRs)
typedef __attribute__((ext_vector_type(4))) float floatx4;    // MFMA C/D + vec loads
typedef __attribute__((ext_vector_type(2))) _Float16 half2v;  // v_dot2 operand

struct KParams {
  const float* x;      // (B,T,D) fp32
  const float* mem;    // (B,S,D) fp32
  const int*   lens;
  const float* W_ih;   // (4D, 2D)
  const float* W_hh;   // (4D, D)
  const float* b_ih;
  const float* b_hh;
  const float* Wg_w;   // (48, D)
  const float* Wg_b;
  float* out;
  unsigned* bar;        // flag barrier region (zeroed each call)
  unsigned short* xc0;  // (B, 2048) bf16 recurrent state [ctx|h]
  unsigned short* xc1;
};

__device__ __forceinline__ float sigf(float v) {
  return __builtin_amdgcn_rcpf(1.0f + __expf(-v));
}
__device__ __forceinline__ float tanhfast(float v) {  // exp/rcp tanh, no libm
  float a = fabsf(v);
  float e = __expf(-2.0f * a);
  float r = (1.0f - e) * __builtin_amdgcn_rcpf(1.0f + e);
  return v < 0.0f ? -r : r;
}

__device__ __forceinline__ unsigned short f2bf(float f) {  // RNE fp32->bf16
  unsigned u = __float_as_uint(f);
  return (unsigned short)((u + 0x7FFFu + ((u >> 16) & 1u)) >> 16);
}
__device__ __forceinline__ unsigned pack2bf(float a, float b) {
  return (unsigned)f2bf(a) | ((unsigned)f2bf(b) << 16);
}
// HW packed RNE fp32->2xbf16 (same rounding as f2bf, 1 instr)
__device__ __forceinline__ unsigned cvtpk(float a, float b) {
  unsigned r;
  asm volatile("v_cvt_pk_bf16_f32 %0, %1, %2" : "=v"(r) : "v"(a), "v"(b));
  return r;
}

// Agent-scope relaxed atomics: uncached loads/stores at the LLC coherence point.
__device__ __forceinline__ void cstore_u32(unsigned* p2, unsigned v) {
  __hip_atomic_store(p2, v, __ATOMIC_RELAXED, __HIP_MEMORY_SCOPE_AGENT);
}
__device__ __forceinline__ unsigned cload_u32(const unsigned* p2) {
  return __hip_atomic_load(p2, __ATOMIC_RELAXED, __HIP_MEMORY_SCOPE_AGENT);
}
__device__ __forceinline__ unsigned long long cload_u64(const unsigned long long* p2) {
  return __hip_atomic_load(p2, __ATOMIC_RELAXED, __HIP_MEMORY_SCOPE_AGENT);
}

// LDS-only barrier: s_barrier without the vmcnt(0) drain __syncthreads implies —
// outstanding global loads ride across phase-C stage barriers.
__device__ __forceinline__ void lds_barrier() {
  asm volatile("s_waitcnt lgkmcnt(0)\n\ts_barrier" ::: "memory");
}

// Decentralized 1-hop grid barrier: 128 flags, 128 parallel pollers (1 flag each).
__device__ __forceinline__ void grid_barrier(unsigned* bar, unsigned ep, int blk) {
  __syncthreads();
  if (threadIdx.x == 0) cstore_u32(&bar[64 + blk * 32], ep);
  if (threadIdx.x < NBLK) {
    while (cload_u32(&bar[64 + (int)threadIdx.x * 32]) < ep) __builtin_amdgcn_s_sleep(1);
  }
  __syncthreads();
}

union UF { unsigned w[4]; unsigned long long u[2]; short8 s; };

#define MFMA16 __builtin_amdgcn_mfma_f32_16x16x32_bf16

// 16 MFMAs: x-region (bfr 0-3 / 12-15) + h-region (bfr 8-11 / 20-23), 2 column-tiles.
__device__ __forceinline__ void xh_mfma(const UF* xf, const UF* hf, const short8* bfr,
                                        floatx4& a00, floatx4& a01,
                                        floatx4& a10, floatx4& a11) {
  floatx4 z = {0.f, 0.f, 0.f, 0.f};
  a00 = z; a01 = z; a10 = z; a11 = z;
  a00 = MFMA16(xf[0].s, bfr[0],  a00, 0, 0, 0); a01 = MFMA16(xf[1].s, bfr[1],  a01, 0, 0, 0);
  a10 = MFMA16(xf[0].s, bfr[12], a10, 0, 0, 0); a11 = MFMA16(xf[1].s, bfr[13], a11, 0, 0, 0);
  a00 = MFMA16(xf[2].s, bfr[2],  a00, 0, 0, 0); a01 = MFMA16(xf[3].s, bfr[3],  a01, 0, 0, 0);
  a10 = MFMA16(xf[2].s, bfr[14], a10, 0, 0, 0); a11 = MFMA16(xf[3].s, bfr[15], a11, 0, 0, 0);
  a00 = MFMA16(hf[0].s, bfr[8],  a00, 0, 0, 0); a01 = MFMA16(hf[1].s, bfr[9],  a01, 0, 0, 0);
  a10 = MFMA16(hf[0].s, bfr[20], a10, 0, 0, 0); a11 = MFMA16(hf[1].s, bfr[21], a11, 0, 0, 0);
  a00 = MFMA16(hf[2].s, bfr[10], a00, 0, 0, 0); a01 = MFMA16(hf[3].s, bfr[11], a01, 0, 0, 0);
  a10 = MFMA16(hf[2].s, bfr[22], a10, 0, 0, 0); a11 = MFMA16(hf[3].s, bfr[23], a11, 0, 0, 0);
}

__device__ __forceinline__ float sel4(const floatx4& v, int r) {  // wave-uniform r
  return (r == 0) ? v[0] : (r == 1) ? v[1] : (r == 2) ? v[2] : v[3];
}

__global__ __launch_bounds__(NTHR, 2) void tts_kernel(KParams p) {
  extern __shared__ char smem[];
  half2v* memsh2 = (half2v*)smem;  // [256 s-pairs][128 d] fp16x2, 128 KiB

  __shared__ float redC[64 * 65 + 4];     // wave-partial C tiles (8w x 2tiles x 4reg)
  __shared__ float phiP[384];             // phi wave-partials [w][48]
  __shared__ float alsh[16], ksish[16], invbsh[16];
  __shared__ float Rsh[513];              // Rsh[s+1]=R(s); Rsh[0]=R(-1)
  __shared__ half2v wsh2[256];            // w(s) packed in s-pairs
  __shared__ float ctxp[4][128];
  __shared__ float bsh48[48];             // Wg_b

  const int t    = threadIdx.x;
  const int blk  = blockIdx.x;
  const int lane = t & 63;
  const int w    = t >> 6;     // wave id [0,8): K-slice w*128 in each region
  const int bbt  = blk & 15;   // batch this block serves in phase C
  const int dc   = blk >> 4;   // [0,8): 128-wide d-chunk for ctx

  // ---- one-time: gate B-fragments (weights), 2 column-tiles x 12 chunks ----
  // tile nt covers W-rows r = (n&3)*1024 + blk*8 + nt*4 + (n>>2), n = lane&15.
  // chunk ki: region ki>>2 (0=x,1=ctx,2=h), k0 = (ki>>2)*1024 + w*128 + (ki&3)*32
  short8 bfr[24];
  {
    const int n = lane & 15;
    const int q = lane >> 4;
#pragma unroll
    for (int nt = 0; nt < 2; ++nt) {
      const int r = (n & 3) * 1024 + blk * 8 + nt * 4 + (n >> 2);
#pragma unroll
      for (int ki = 0; ki < 12; ++ki) {
        short8 v;
        const int k0 = (ki >> 2) * 1024 + w * 128 + (ki & 3) * 32 + q * 8;
#pragma unroll
        for (int j = 0; j < 8; ++j) {
          int k = k0 + j;
          float wv = (k < 2048) ? p.W_ih[(size_t)r * 2048 + k]
                                : p.W_hh[(size_t)r * 1024 + (k - 2048)];
          v[j] = (short)f2bf(wv);
        }
        bfr[nt * 12 + ki] = v;
      }
    }
  }
  // ---- one-time: phi B-fragments: wgB[tau*4+c] = Wg_w rows tau*16..+16, k-chunk c ----
  // B[k][n]: lane holds B[w*128 + c*32 + (lane>>4)*8 + j][lane&15] = Wg_w[tau*16+(lane&15)][k]
  short8 wgB[12];
  {
    const int n = lane & 15;
    const int q = lane >> 4;
#pragma unroll
    for (int tau = 0; tau < 3; ++tau)
#pragma unroll
      for (int c = 0; c < 4; ++c) {
        short8 v;
        const float* wg = p.Wg_w + (size_t)(tau * 16 + n) * 1024 + w * 128 + c * 32 + q * 8;
#pragma unroll
        for (int j = 0; j < 8; ++j) v[j] = (short)f2bf(wg[j]);
        wgB[tau * 4 + c] = v;
      }
  }
  // ---- one-time: biases for (b = t>>3, dl = t&7) ----
  float biasreg[4] = {0.f, 0.f, 0.f, 0.f};
  if (t < 128) {
    int dl = t & 7;
#pragma unroll
    for (int g = 0; g < 4; ++g) {
      int r = g * 1024 + blk * 8 + dl;
      biasreg[g] = p.b_ih[r] + p.b_hh[r];
    }
  }
  if (t < 48) bsh48[t] = p.Wg_b[t];
  // ---- one-time: memory[bbt, :, dc*128..+128) -> LDS as half2 s-pairs ----
  {
    int dl = t & 127, sp = t >> 7;
    for (int pr = sp; pr < 256; pr += 4) {
      const float* mp = p.mem + (size_t)bbt * SS * DD + (size_t)(2 * pr) * DD + dc * 128 + dl;
      half2v v;
      v.x = (_Float16)mp[0];
      v.y = (_Float16)mp[DD];
      memsh2[pr * 128 + dl] = v;
    }
  }

  float c_val = 0.0f;  // LSTM cell state: thread t<128 owns (b=t>>3, d=blk*8+(t&7))
  unsigned ep = 0;
  unsigned short* xc_cur = p.xc0;
  unsigned short* xc_nxt = p.xc1;
  // per-lane fragment bases: A-row = batch = lane&15, k = w*128 + (lane>>4)*8
  const int ab2 = ((lane & 15) * KK2 + w * 128 + ((lane >> 4) * 8)) >> 2;  // u64 units
  const float* xrow = p.x + (size_t)(lane & 15) * TT * DD + w * 128 + ((lane >> 4) * 8);

  // Pre-loop: x_0 (direct, cacheable) + h_{-1}(=0, host-zeroed xc0) contributions.
  floatx4 acc00, acc01, acc10, acc11;
  {
    UF xf[4], hf[4];
#pragma unroll
    for (int sub = 0; sub < 4; ++sub) {
      floatx4 lo = *(const floatx4*)(xrow + sub * 32);
      floatx4 hi = *(const floatx4*)(xrow + sub * 32 + 4);
      xf[sub].w[0] = cvtpk(lo[0], lo[1]); xf[sub].w[1] = cvtpk(lo[2], lo[3]);
      xf[sub].w[2] = cvtpk(hi[0], hi[1]); xf[sub].w[3] = cvtpk(hi[2], hi[3]);
    }
    const unsigned long long* hb = (const unsigned long long*)p.xc0 + ab2 + 256;
#pragma unroll
    for (int sub = 0; sub < 4; ++sub) {
      hf[sub].u[0] = cload_u64(hb + sub * 8);
      hf[sub].u[1] = cload_u64(hb + sub * 8 + 1);
    }
    xh_mfma(xf, hf, bfr, acc00, acc01, acc10, acc11);
  }

  for (int tstep = 0; tstep < TT; ++tstep) {
    // ================= Phase A: ctx-part MFMA + LSTM pointwise =================
    {
      const unsigned long long* cb = (const unsigned long long*)xc_cur + ab2;
      UF fc[4];
#pragma unroll
      for (int sub = 0; sub < 4; ++sub) {
        fc[sub].u[0] = cload_u64(cb + sub * 8);
        fc[sub].u[1] = cload_u64(cb + sub * 8 + 1);
      }
      floatx4 c00 = acc00, c01 = acc01, c10 = acc10, c11 = acc11;
      c00 = MFMA16(fc[0].s, bfr[4],  c00, 0, 0, 0); c01 = MFMA16(fc[1].s, bfr[5],  c01, 0, 0, 0);
      c10 = MFMA16(fc[0].s, bfr[16], c10, 0, 0, 0); c11 = MFMA16(fc[1].s, bfr[17], c11, 0, 0, 0);
      c00 = MFMA16(fc[2].s, bfr[6],  c00, 0, 0, 0); c01 = MFMA16(fc[3].s, bfr[7],  c01, 0, 0, 0);
      c10 = MFMA16(fc[2].s, bfr[18], c10, 0, 0, 0); c11 = MFMA16(fc[3].s, bfr[19], c11, 0, 0, 0);
      c00 += c01; c10 += c11;
#pragma unroll
      for (int reg = 0; reg < 4; ++reg) {
        redC[(w * 8 + reg) * 65 + lane]     = c00[reg];
        redC[(w * 8 + 4 + reg) * 65 + lane] = c10[reg];
      }
    }
    lds_barrier();
    if (t < 128) {  // pointwise LSTM for (b = t>>3, dl = t&7)
      int b = t >> 3, dl = t & 7, nt = dl >> 2, dl4 = dl & 3;
      int row = nt * 4 + (b & 3);
      float gate[4];
#pragma unroll
      for (int g = 0; g < 4; ++g) {
        int ls = ((b >> 2) << 4) | (dl4 * 4 + g);
        float s = biasreg[g];
#pragma unroll
        for (int w2 = 0; w2 < 8; ++w2) s += redC[(w2 * 8 + row) * 65 + ls];
        gate[g] = s;
      }
      c_val = sigf(gate[1]) * c_val + sigf(gate[0]) * tanhfast(gate[2]);
      float hv = sigf(gate[3]) * tanhfast(c_val);
      float hn = __shfl_down(hv, 1, 64);
      if ((t & 1) == 0)
        cstore_u32((unsigned*)(xc_nxt + b * KK2 + 1024 + blk * 8 + dl), pack2bf(hv, hn));
    }
    grid_barrier(p.bar, ++ep, blk);  // barH: h_t globally visible

    // ============ Phase C: phi(MFMA) -> softmax -> R/w -> ctx; gate MFMA rides ============
    // h_t fragments (agent, critical path: feed phi MFMAs AND next-step gate MFMAs)
    UF hf[4];
    {
      const unsigned long long* hb = (const unsigned long long*)xc_nxt + ab2 + 256;
#pragma unroll
      for (int sub = 0; sub < 4; ++sub) {
        hf[sub].u[0] = cload_u64(hb + sub * 8);
        hf[sub].u[1] = cload_u64(hb + sub * 8 + 1);
      }
    }
    // x_{t+1} (plain fp32, L2-cacheable), converted immediately to bf16 frags
    UF xf[4];
    if (tstep + 1 < TT) {
      const float* xp = xrow + (size_t)(tstep + 1) * DD;
#pragma unroll
      for (int sub = 0; sub < 4; ++sub) {
        floatx4 lo = *(const floatx4*)(xp + sub * 32);
        floatx4 hi = *(const floatx4*)(xp + sub * 32 + 4);
        xf[sub].w[0] = cvtpk(lo[0], lo[1]); xf[sub].w[1] = cvtpk(lo[2], lo[3]);
        xf[sub].w[2] = cvtpk(hi[0], hi[1]); xf[sub].w[3] = cvtpk(hi[2], hi[3]);
      }
    }
    // phi = h x Wg^T via 12 MFMAs/wave (K-slice w*128..+128), D rows = batches.
    {
      floatx4 z = {0.f, 0.f, 0.f, 0.f};
      floatx4 ph0 = z, ph1 = z, ph2 = z;
      ph0 = MFMA16(hf[0].s, wgB[0], ph0, 0, 0, 0);
      ph1 = MFMA16(hf[0].s, wgB[4], ph1, 0, 0, 0);
      ph2 = MFMA16(hf[0].s, wgB[8], ph2, 0, 0, 0);
      ph0 = MFMA16(hf[1].s, wgB[1], ph0, 0, 0, 0);
      ph1 = MFMA16(hf[1].s, wgB[5], ph1, 0, 0, 0);
      ph2 = MFMA16(hf[1].s, wgB[9], ph2, 0, 0, 0);
      ph0 = MFMA16(hf[2].s, wgB[2], ph0, 0, 0, 0);
      ph1 = MFMA16(hf[2].s, wgB[6], ph1, 0, 0, 0);
      ph2 = MFMA16(hf[2].s, wgB[10], ph2, 0, 0, 0);
      ph0 = MFMA16(hf[3].s, wgB[3], ph0, 0, 0, 0);
      ph1 = MFMA16(hf[3].s, wgB[7], ph1, 0, 0, 0);
      ph2 = MFMA16(hf[3].s, wgB[11], ph2, 0, 0, 0);
      // D[m=batch][n]: lane&15 = n, (lane>>4)*4+reg = m. Keep only m = bbt.
      if ((lane >> 4) == (bbt >> 2)) {
        int m = lane & 15, r = bbt & 3;
        phiP[w * 48 + m]      = sel4(ph0, r);
        phiP[w * 48 + 16 + m] = sel4(ph1, r);
        phiP[w * 48 + 32 + m] = sel4(ph2, r);
      }
    }
    lds_barrier();
    if (t < 64) {  // merged: phi reduce + softmax + exps + R(-1), all in wave 0
      float s = 0.f;
      if (t < 48) {
        s = bsh48[t];
#pragma unroll
        for (int i = 0; i < 8; ++i) s += phiP[i * 48 + t];
      }
      float mx = s;
#pragma unroll
      for (int o = 1; o < 16; o <<= 1) mx = fmaxf(mx, __shfl_xor(mx, o, 64));
      float e = __expf(s - mx);
      float sm = e;
#pragma unroll
      for (int o = 1; o < 16; o <<= 1) sm += __shfl_xor(sm, o, 64);
      float alpha_v = e * __builtin_amdgcn_rcpf(sm);
      float ksi_v   = __expf(s);
      float invb_v  = __expf(-s);
      if (t >= 32) { if (t < 48) alsh[t - 32] = alpha_v; }
      else if (t < 16) ksish[t] = ksi_v;
      else invbsh[t - 16] = invb_v;
      int m = t & 15;
      float am = __shfl(alpha_v, 32 + m, 64);
      float km = __shfl(ksi_v, m, 64);
      float bm = __shfl(invb_v, 16 + m, 64);
      float term = am * sigf((-0.5f - km) * bm);
#pragma unroll
      for (int o = 1; o < 16; o <<= 1) term += __shfl_xor(term, o, 64);
      if (t == 48) Rsh[0] = term;
    }
    lds_barrier();
    {  // R(s) + w(s)=R(s)-R(s-1) via in-wave shuffles; pack wsh2; alignment store
      float su = (float)t;
      float rv0 = 0.f, rv1 = 0.f;
#pragma unroll
      for (int m = 0; m < 16; m += 2) {
        rv0 += alsh[m]     * sigf((su + 0.5f - ksish[m])     * invbsh[m]);
        rv1 += alsh[m + 1] * sigf((su + 0.5f - ksish[m + 1]) * invbsh[m + 1]);
      }
      float rv = rv0 + rv1;
      float rvp = __shfl_up(rv, 1, 64);   // invalid at lane 0 — fixed below via Rsh
      float rvn = __shfl_down(rv, 1, 64);
      Rsh[t + 1] = rv;
      if ((t & 1) == 0) {
        half2v v2;
        v2.x = (_Float16)(rv - rvp);
        v2.y = (_Float16)(rvn - rv);
        wsh2[t >> 1] = v2;
      }
      if (dc == 0 && (t & 63) != 0)
        p.out[OUT_ALIGN + ((size_t)bbt * TT + tstep) * SS + t] = rv - rvp;
    }
    lds_barrier();
    {  // ctx partials; wave-boundary w entries (pr%32==0) recomputed from Rsh
      if (dc == 0 && t < 8)
        p.out[OUT_ALIGN + ((size_t)bbt * TT + tstep) * SS + 64 * t] =
            Rsh[64 * t + 1] - Rsh[64 * t];
      if (tstep == TT - 1 && dc == 0 && t == 0)
        p.out[OUT_TERM + bbt] = 1.0f - Rsh[p.lens[bbt]];
      int dl = t & 127, sp = t >> 7;
      const int pb = sp * 64;
      half2v wa = wsh2[pb];       wa.x = (_Float16)(Rsh[2 * pb + 1] - Rsh[2 * pb]);
      half2v wb = wsh2[pb + 32];  wb.x = (_Float16)(Rsh[2 * pb + 65] - Rsh[2 * pb + 64]);
      float s0 = __builtin_amdgcn_fdot2(memsh2[pb * 128 + dl], wa, 0.f, false);
      float s1 = __builtin_amdgcn_fdot2(memsh2[(pb + 32) * 128 + dl], wb, 0.f, false);
#pragma unroll 8
      for (int q = 1; q < 32; ++q) {
        s0 = __builtin_amdgcn_fdot2(memsh2[(pb + q) * 128 + dl],      wsh2[pb + q],      s0, false);
        s1 = __builtin_amdgcn_fdot2(memsh2[(pb + 32 + q) * 128 + dl], wsh2[pb + 32 + q], s1, false);
      }
      ctxp[sp][dl] = s0 + s1;
    }
    lds_barrier();
    if (t < 128) {  // ctx reduce + agent store (+ context output at last step)
      float cv = ctxp[0][t] + ctxp[1][t] + ctxp[2][t] + ctxp[3][t];
      if (tstep == TT - 1) p.out[bbt * DD + dc * 128 + t] = cv;
      float cvn = __shfl_down(cv, 1, 64);
      if ((t & 1) == 0)
        cstore_u32((unsigned*)(xc_nxt + bbt * KK2 + dc * 128 + t), pack2bf(cv, cvn));
    }
    // next-step x/h gate MFMAs (register-only; hf/xf already in VGPRs).
    __builtin_amdgcn_sched_barrier(0);
    if (tstep + 1 < TT) {
      xh_mfma(xf, hf, bfr, acc00, acc01, acc10, acc11);
    }
    grid_barrier(p.bar, ++ep, blk);  // barE: ctx_t globally visible

    unsigned short* tmp = xc_cur; xc_cur = xc_nxt; xc_nxt = tmp;
  }
}

extern "C" void kernel_launch(void* const* d_in, const int* in_sizes, int n_in,
                              void* d_out, int out_size, void* d_ws, size_t ws_size,
                              hipStream_t stream) {
  (void)in_sizes; (void)n_in; (void)out_size; (void)ws_size;
  KParams p;
  p.x    = (const float*)d_in[0];
  p.mem  = (const float*)d_in[1];
  p.lens = (const int*)d_in[2];
  p.W_ih = (const float*)d_in[3];
  p.W_hh = (const float*)d_in[4];
  p.b_ih = (const float*)d_in[5];
  p.b_hh = (const float*)d_in[6];
  p.Wg_w = (const float*)d_in[7];
  p.Wg_b = (const float*)d_in[8];
  p.out  = (float*)d_out;
  p.bar  = (unsigned*)d_ws;
  p.xc0  = (unsigned short*)((char*)d_ws + 36864);                  // 16*2048*2 = 64 KiB
  p.xc1  = (unsigned short*)((char*)d_ws + 36864 + 65536);

  // zero barrier flags + xc0 (ctx_{-1} = h_{-1} = 0)
  hipMemsetAsync(d_ws, 0, 36864 + 65536, stream);

  const unsigned dynLds = 131072;  // half2 memory slice [256][128]
  hipFuncSetAttribute((const void*)tts_kernel, hipFuncAttributeMaxDynamicSharedMemorySize,
                      (int)dynLds);

  void* args[] = { &p };
  hipLaunchCooperativeKernel((const void*)tts_kernel, dim3(NBLK), dim3(NTHR), args, dynLds,
                             stream);
}